// Round 2
// baseline (3525.697 us; speedup 1.0000x reference)
//
#include <hip/hip_runtime.h>
#include <hip/hip_bf16.h>
#include <hip/hip_cooperative_groups.h>
#include <float.h>

namespace cg = cooperative_groups;

// Problem constants (OSG_C_29987461660961)
#define NTOK 2048
#define FDIM 1024
#define HDIM 512
#define EDIM 256
#define BATCH 2
#define KSEG 30
#define NP1 2049
static const size_t ST2 = (size_t)NP1 * NP1;   // Sp per-batch element count

// ---------------------------------------------------------------------------
// Shared NT GEMM: C[i][j] = sum_k A[i*lda+k]*B[j*ldb+k]  (+bias / relu / D-xform)
// MODE 0: bias+relu (h), MODE 1: bias (e), MODE 2: corr -> D epilogue
// ---------------------------------------------------------------------------
template<int MODE>
__global__ __launch_bounds__(256)
void gemm_nt(const float* __restrict__ A, int lda, size_t strideA,
             const float* __restrict__ Bm, int ldb, size_t strideB,
             const float* __restrict__ bias,
             float* __restrict__ C, int ldc, size_t strideC,
             int K, const float* __restrict__ dvec)
{
    __shared__ float As[32][68];
    __shared__ float Bs[32][68];
    const int z = blockIdx.z;
    const float* Ab = A + (size_t)z * strideA;
    const float* Bb = Bm + (size_t)z * strideB;
    float* Cb = C + (size_t)z * strideC;

    const int t = threadIdx.x;
    const int tx = t & 15, ty = t >> 4;
    const int lrow = t >> 3, lkv = t & 7;
    const int by = blockIdx.y, bx = blockIdx.x;

    float acc[4][4] = {};
    const int ktiles = K >> 5;
    for (int kt = 0; kt < ktiles; ++kt) {
#pragma unroll
        for (int h = 0; h < 2; ++h) {
            const int r = lrow + h * 32;
            const float4 av = *(const float4*)(Ab + (size_t)(by * 64 + r) * lda + kt * 32 + lkv * 4);
            As[lkv * 4 + 0][r] = av.x; As[lkv * 4 + 1][r] = av.y;
            As[lkv * 4 + 2][r] = av.z; As[lkv * 4 + 3][r] = av.w;
            const float4 bv = *(const float4*)(Bb + (size_t)(bx * 64 + r) * ldb + kt * 32 + lkv * 4);
            Bs[lkv * 4 + 0][r] = bv.x; Bs[lkv * 4 + 1][r] = bv.y;
            Bs[lkv * 4 + 2][r] = bv.z; Bs[lkv * 4 + 3][r] = bv.w;
        }
        __syncthreads();
#pragma unroll
        for (int kk = 0; kk < 32; ++kk) {
            const float4 a = *(const float4*)&As[kk][ty * 4];
            const float4 b = *(const float4*)&Bs[kk][tx * 4];
            const float ar[4] = {a.x, a.y, a.z, a.w};
            const float br[4] = {b.x, b.y, b.z, b.w};
#pragma unroll
            for (int i = 0; i < 4; ++i)
#pragma unroll
                for (int j = 0; j < 4; ++j)
                    acc[i][j] = fmaf(ar[i], br[j], acc[i][j]);
        }
        __syncthreads();
    }

    const int row0 = by * 64 + ty * 4;
    const int col0 = bx * 64 + tx * 4;
    if (MODE == 2) {
        float di[4], dj[4];
#pragma unroll
        for (int i = 0; i < 4; ++i) di[i] = dvec[z * NTOK + row0 + i];
#pragma unroll
        for (int j = 0; j < 4; ++j) dj[j] = dvec[z * NTOK + col0 + j];
#pragma unroll
        for (int i = 0; i < 4; ++i) {
            float4 v;
            float o[4];
#pragma unroll
            for (int j = 0; j < 4; ++j) {
                const float den = sqrtf(fmaxf(di[i] * dj[j], 1e-8f));
                o[j] = 0.5f * (1.0f - acc[i][j] / den);
            }
            v.x = o[0]; v.y = o[1]; v.z = o[2]; v.w = o[3];
            *(float4*)(Cb + (size_t)(row0 + i) * ldc + col0) = v;
        }
    } else {
#pragma unroll
        for (int i = 0; i < 4; ++i) {
            float o[4];
#pragma unroll
            for (int j = 0; j < 4; ++j) {
                float v = acc[i][j] + bias[col0 + j];
                if (MODE == 0) v = fmaxf(v, 0.0f);
                o[j] = v;
            }
            float4 v4; v4.x = o[0]; v4.y = o[1]; v4.z = o[2]; v4.w = o[3];
            *(float4*)(Cb + (size_t)(row0 + i) * ldc + col0) = v4;
        }
    }
}

__global__ __launch_bounds__(256)
void rownorm_kernel(const float* __restrict__ e, float* __restrict__ dvec)
{
    const int wid = (blockIdx.x * 256 + threadIdx.x) >> 6;
    const int lane = threadIdx.x & 63;
    if (wid >= BATCH * NTOK) return;
    const float4 v = *(const float4*)(e + (size_t)wid * EDIM + lane * 4);
    float s = v.x * v.x + v.y * v.y + v.z * v.z + v.w * v.w;
#pragma unroll
    for (int off = 32; off; off >>= 1) s += __shfl_xor(s, off);
    if (lane == 0) dvec[wid] = s;
}

// Row-wise inclusive scan of D (f32) into Sp rows 1..N (f64). Sp[r][0]=0.
__global__ __launch_bounds__(256)
void sat_row_kernel(const float* __restrict__ D, double* __restrict__ Sp)
{
    const int b = blockIdx.y;
    const int r = blockIdx.x + 1;
    const float* drow = D + (size_t)b * NTOK * NTOK + (size_t)(r - 1) * NTOK;
    double* sprow = Sp + (size_t)b * ST2 + (size_t)r * NP1;
    const int t = threadIdx.x, lane = t & 63, wv = t >> 6;
    __shared__ double wtot[4];
    double carry = 0.0;
    if (t == 0) sprow[0] = 0.0;
    for (int ch = 0; ch < NTOK / 256; ++ch) {
        double v = (double)drow[ch * 256 + t];
#pragma unroll
        for (int d = 1; d < 64; d <<= 1) {
            const double u = __shfl_up(v, (unsigned)d, 64);
            if (lane >= d) v += u;
        }
        if (lane == 63) wtot[wv] = v;
        __syncthreads();
        double pre = carry;
        for (int ww = 0; ww < wv; ++ww) pre += wtot[ww];
        const double tot = carry + wtot[0] + wtot[1] + wtot[2] + wtot[3];
        sprow[ch * 256 + t + 1] = v + pre;
        __syncthreads();
        carry = tot;
    }
}

// Column cumsum of Sp in 3 phases (strips of 256 rows).
__global__ void satc1(const double* __restrict__ Sp, double* __restrict__ aux)
{
    const int b = blockIdx.z, s = blockIdx.y;
    const int c = blockIdx.x * 256 + threadIdx.x;
    if (c > NTOK) return;
    const double* sp = Sp + (size_t)b * ST2;
    double tt = 0.0;
    const int r0 = s * 256 + 1;
    for (int r = r0; r < r0 + 256; ++r) tt += sp[(size_t)r * NP1 + c];
    aux[(size_t)(b * 8 + s) * NP1 + c] = tt;
}
__global__ void satc2(double* __restrict__ aux)
{
    const int b = blockIdx.y;
    const int c = blockIdx.x * 256 + threadIdx.x;
    if (c > NTOK) return;
    double run = 0.0;
    for (int s = 0; s < 8; ++s) {
        const size_t id = (size_t)(b * 8 + s) * NP1 + c;
        const double tt = aux[id]; aux[id] = run; run += tt;
    }
}
__global__ void satc3(double* __restrict__ Sp, const double* __restrict__ aux)
{
    const int b = blockIdx.z, s = blockIdx.y;
    const int c = blockIdx.x * 256 + threadIdx.x;
    if (c > NTOK) return;
    double* sp = Sp + (size_t)b * ST2;
    if (s == 0) sp[c] = 0.0;
    double run = aux[(size_t)(b * 8 + s) * NP1 + c];
    const int r0 = s * 256 + 1;
    for (int r = r0; r < r0 + 256; ++r) {
        const size_t id = (size_t)r * NP1 + c;
        run += sp[id];
        sp[id] = run;
    }
}

__global__ void diag_kernel(const double* __restrict__ Sp, double* __restrict__ dg)
{
    const int b = blockIdx.y;
    const int t = blockIdx.x * 256 + threadIdx.x;
    if (t <= NTOK) dg[b * NP1 + t] = Sp[(size_t)b * ST2 + (size_t)t * NP1 + t];
}

// Bsum[i][j] = diag[j+1] + diag[i] - 2*Sp[i][j+1] (f64 math -> f32), j >= i.
__global__ __launch_bounds__(256)
void bsum_kernel(const double* __restrict__ Sp, const double* __restrict__ dg,
                 float* __restrict__ Bsum, float* __restrict__ C0)
{
    const int b = blockIdx.y, i = blockIdx.x;
    const double* sprow = Sp + (size_t)b * ST2 + (size_t)i * NP1;
    const double* dgb = dg + (size_t)b * NP1;
    const double di = dgb[i];
    float* brow = Bsum + (size_t)b * NTOK * NTOK + (size_t)i * NTOK;
    for (int j = i + threadIdx.x; j < NTOK; j += 256) {
        const double v = dgb[j + 1] + di - 2.0 * sprow[j + 1];
        brow[j] = (float)v;
        if (j == NTOK - 1) C0[b * NTOK + i] = (float)v;
    }
}

// ---------------------------------------------------------------------------
// Fused DP: all 29 steps in one cooperative kernel. Each wave owns row pair
// (p, 2047-p) -> exactly 2049 Bsum elements, parked in LDS for all steps.
// Per step: min-reduce (DP value = softmax pivot), exp pass accumulating into
// per-block LDS acc (summed across steps), C vector exchanged via global +
// grid.sync(). acc merged to global tsum once at the end.
// Grid: (256, BATCH) x 256 thr. LDS 49.2KB -> 2 blocks/CU co-resident.
// ---------------------------------------------------------------------------
__global__ __launch_bounds__(256)
void dp_fused_kernel(const float* __restrict__ Bsum,
                     float* __restrict__ Ca, float* __restrict__ Cb,
                     float* __restrict__ tsum)
{
    __shared__ float rowbuf[4][2052];
    __shared__ float cs[NTOK];
    __shared__ float acc[NTOK];
    const int b = blockIdx.y;
    const int t = threadIdx.x, lane = t & 63, wv = t >> 6;
    const int p = blockIdx.x * 4 + wv;       // pair id 0..1023
    const int i0 = p, i1 = NTOK - 1 - p;
    const int L0 = NTOK - p;                 // length of row i0 (cols p..2047)
    const float* Bb = Bsum + (size_t)b * NTOK * NTOK;
    float* rb = rowbuf[wv];
    // combined load: idx<L0 -> row i0 col p+idx ; else row i1 col idx-1
    for (int idx = lane; idx < NTOK + 1; idx += 64) {
        rb[idx] = (idx < L0) ? Bb[(size_t)i0 * NTOK + p + idx]
                             : Bb[(size_t)i1 * NTOK + (idx - 1)];
    }
    for (int j = t; j < NTOK; j += 256) acc[j] = 0.0f;
    __syncthreads();
    // C0[i] = Bsum[i][N-1]
    if (lane == 0) {
        Ca[b * NTOK + i0] = rb[L0 - 1];
        Ca[b * NTOK + i1] = rb[NTOK];
    }
    __threadfence();
    cg::this_grid().sync();

    const float* Cr = Ca;
    float* Cn = Cb;
    for (int k = 1; k < KSEG; ++k) {
        const float* Crb = Cr + b * NTOK;
        for (int j = t; j < NTOK; j += 256)
            cs[j] = (j < NTOK - 1) ? Crb[j + 1] : 0.0f;
        __syncthreads();
        const int jmax = NTOK - k;
        float* Cnb = Cn + b * NTOK;
        // ---- row i0 = p (always valid: p <= 1023 < jmax) ----
        {
            const int V = jmax - p;
            float mv[32];
            float mn = FLT_MAX;
#pragma unroll
            for (int c = 0; c < 32; ++c) {
                const int idx = lane + c * 64;
                float v = FLT_MAX;
                if (idx < V) v = rb[idx] + cs[p + idx];
                mv[c] = v;
                mn = fminf(mn, v);
            }
#pragma unroll
            for (int off = 32; off; off >>= 1) mn = fminf(mn, __shfl_xor(mn, off));
            if (lane == 0) Cnb[i0] = mn;
            float s = 0.0f;
#pragma unroll
            for (int c = 0; c < 32; ++c) {
                const int idx = lane + c * 64;
                float w = 0.0f;
                if (idx < V) w = __expf(mn - mv[c]);
                mv[c] = w;
                s += w;
            }
#pragma unroll
            for (int off = 32; off; off >>= 1) s += __shfl_xor(s, off);
            const float inv = 1.0f / s;
#pragma unroll
            for (int c = 0; c < 32; ++c) {
                const int idx = lane + c * 64;
                if (idx < V) atomicAdd(&acc[p + idx], mv[c] * inv);
            }
        }
        // ---- row i1 = 2047-p (valid iff p >= k) ----
        if (p >= k) {
            const int V = p + 1 - k;
            float mv[16];
            float mn = FLT_MAX;
#pragma unroll
            for (int c = 0; c < 16; ++c) {
                const int idx = lane + c * 64;
                float v = FLT_MAX;
                if (idx < V) v = rb[L0 + idx] + cs[i1 + idx];
                mv[c] = v;
                mn = fminf(mn, v);
            }
#pragma unroll
            for (int off = 32; off; off >>= 1) mn = fminf(mn, __shfl_xor(mn, off));
            if (lane == 0) Cnb[i1] = mn;
            float s = 0.0f;
#pragma unroll
            for (int c = 0; c < 16; ++c) {
                const int idx = lane + c * 64;
                float w = 0.0f;
                if (idx < V) w = __expf(mn - mv[c]);
                mv[c] = w;
                s += w;
            }
#pragma unroll
            for (int off = 32; off; off >>= 1) s += __shfl_xor(s, off);
            const float inv = 1.0f / s;
#pragma unroll
            for (int c = 0; c < 16; ++c) {
                const int idx = lane + c * 64;
                if (idx < V) atomicAdd(&acc[i1 + idx], mv[c] * inv);
            }
        } else if (lane == 0) {
            Cnb[i1] = 0.0f;
        }
        __threadfence();
        cg::this_grid().sync();
        float* tmp = (float*)Cr; Cr = Cn; Cn = tmp;
    }
    // merge per-block acc into global tsum
    __syncthreads();
    float* ts = tsum + b * NTOK;
    for (int j = t; j < NTOK; j += 256) {
        const float v = acc[j];
        if (v != 0.0f) atomicAdd(&ts[j], v);
    }
}

// ---- fallback path (29 launches), kept in case cooperative launch fails ----
__global__ __launch_bounds__(256)
void dp_step_kernel(const float* __restrict__ Bsum, const float* __restrict__ Cprev,
                    float* __restrict__ Cnext, float* __restrict__ tsum, int kk)
{
    __shared__ float cs[NTOK];
    __shared__ float acc[NTOK];
    const int b = blockIdx.y;
    const int t = threadIdx.x, lane = t & 63, wv = t >> 6;
    const float* Cp = Cprev + b * NTOK;
    for (int j = t; j < NTOK; j += 256) {
        cs[j] = (j < NTOK - 1) ? Cp[j + 1] : 0.0f;
        acc[j] = 0.0f;
    }
    __syncthreads();
    const int jmax = NTOK - kk;
    const int w = blockIdx.x * 4 + wv;
    const float* Bb = Bsum + (size_t)b * NTOK * NTOK;
    float* Cn = Cnext + b * NTOK;
    const int rows[4] = { w, 1023 - w, 1024 + w, 2047 - w };
#pragma unroll
    for (int rr = 0; rr < 4; ++rr) {
        const int i = rows[rr];
        if (i >= jmax) { if (lane == 0) Cn[i] = 0.0f; continue; }
        const float* brow = Bb + (size_t)i * NTOK;
        const int j0 = i + lane;
        float mv[32];
        float mn = FLT_MAX;
#pragma unroll
        for (int c = 0; c < 32; ++c) {
            const int j = j0 + c * 64;
            float v = FLT_MAX;
            if (j < jmax) v = brow[j] + cs[j];
            mv[c] = v;
            mn = fminf(mn, v);
        }
#pragma unroll
        for (int off = 32; off; off >>= 1) mn = fminf(mn, __shfl_xor(mn, off));
        if (lane == 0) Cn[i] = mn;
        float s = 0.0f;
#pragma unroll
        for (int c = 0; c < 32; ++c) {
            const int j = j0 + c * 64;
            float p = 0.0f;
            if (j < jmax) p = __expf(mn - mv[c]);
            mv[c] = p;
            s += p;
        }
#pragma unroll
        for (int off = 32; off; off >>= 1) s += __shfl_xor(s, off);
        const float inv = 1.0f / s;
#pragma unroll
        for (int c = 0; c < 32; ++c) {
            const int j = j0 + c * 64;
            if (j < jmax) atomicAdd(&acc[j], mv[c] * inv);
        }
    }
    __syncthreads();
    float* ts = tsum + b * NTOK;
    for (int j = t; j < NTOK; j += 256) {
        const float v = acc[j];
        if (v != 0.0f) atomicAdd(&ts[j], v);
    }
}

__global__ void finalize_kernel(const float* __restrict__ tsum, float* __restrict__ out)
{
    const int b = blockIdx.y;
    const int j = blockIdx.x * 256 + threadIdx.x;
    if (j >= NTOK) return;
    float ts = tsum[b * NTOK + j];
    int steps = NTOK - 1 - j;
    if (steps > KSEG - 1) steps = KSEG - 1;
    float tc = (float)(j + 1) * (float)steps;
    if (j == NTOK - 1) { ts += (float)NTOK; tc += (float)NTOK; }
    out[b * NTOK + j] = ts / tc;
}

extern "C" void kernel_launch(void* const* d_in, const int* in_sizes, int n_in,
                              void* d_out, int out_size, void* d_ws, size_t ws_size,
                              hipStream_t stream)
{
    const float* x  = (const float*)d_in[0];
    const float* W0 = (const float*)d_in[1];
    const float* b0 = (const float*)d_in[2];
    const float* W1 = (const float*)d_in[3];
    const float* b1 = (const float*)d_in[4];
    float* out = (float*)d_out;

    char* ws = (char*)d_ws;
    size_t off = 0;
    auto alloc = [&](size_t bytes) -> void* {
        void* p = (void*)(ws + off);
        off += (bytes + 255) & ~(size_t)255;
        return p;
    };
    double* Sp   = (double*)alloc((size_t)BATCH * ST2 * sizeof(double));
    float*  Dm   = (float*) alloc((size_t)BATCH * NTOK * NTOK * sizeof(float));
    float*  h    = (float*) alloc((size_t)BATCH * NTOK * HDIM * sizeof(float));
    float*  e    = (float*) alloc((size_t)BATCH * NTOK * EDIM * sizeof(float));
    float*  dvec = (float*) alloc((size_t)BATCH * NTOK * sizeof(float));
    double* dg   = (double*)alloc((size_t)BATCH * NP1 * sizeof(double));
    double* aux  = (double*)alloc((size_t)BATCH * 8 * NP1 * sizeof(double));
    float*  CA   = (float*) alloc((size_t)BATCH * NTOK * sizeof(float));
    float*  CB   = (float*) alloc((size_t)BATCH * NTOK * sizeof(float));
    float*  tsum = (float*) alloc((size_t)BATCH * NTOK * sizeof(float));
    (void)ws_size; (void)in_sizes; (void)n_in; (void)out_size;

    hipMemsetAsync(tsum, 0, (size_t)BATCH * NTOK * sizeof(float), stream);

    gemm_nt<0><<<dim3(HDIM / 64, (BATCH * NTOK) / 64, 1), 256, 0, stream>>>(
        x, FDIM, 0, W0, FDIM, 0, b0, h, HDIM, 0, FDIM, nullptr);
    gemm_nt<1><<<dim3(EDIM / 64, (BATCH * NTOK) / 64, 1), 256, 0, stream>>>(
        h, HDIM, 0, W1, HDIM, 0, b1, e, EDIM, 0, HDIM, nullptr);
    rownorm_kernel<<<dim3((BATCH * NTOK) / 4), 256, 0, stream>>>(e, dvec);
    gemm_nt<2><<<dim3(NTOK / 64, NTOK / 64, BATCH), 256, 0, stream>>>(
        e, EDIM, (size_t)NTOK * EDIM, e, EDIM, (size_t)NTOK * EDIM, nullptr,
        Dm, NTOK, (size_t)NTOK * NTOK, EDIM, dvec);
    sat_row_kernel<<<dim3(NTOK, BATCH), 256, 0, stream>>>(Dm, Sp);
    satc1<<<dim3((NP1 + 255) / 256, 8, BATCH), 256, 0, stream>>>(Sp, aux);
    satc2<<<dim3((NP1 + 255) / 256, BATCH), 256, 0, stream>>>(aux);
    satc3<<<dim3((NP1 + 255) / 256, 8, BATCH), 256, 0, stream>>>(Sp, aux);
    diag_kernel<<<dim3((NP1 + 255) / 256, BATCH), 256, 0, stream>>>(Sp, dg);
    bsum_kernel<<<dim3(NTOK, BATCH), 256, 0, stream>>>(Sp, dg, Dm, CA);

    // Fused DP (cooperative). CA doubles as the C0/step buffer A.
    void* args[] = { (void*)&Dm, (void*)&CA, (void*)&CB, (void*)&tsum };
    hipError_t err = hipLaunchCooperativeKernel((const void*)dp_fused_kernel,
                                                dim3(NTOK / 8, BATCH), dim3(256),
                                                args, 0, stream);
    if (err != hipSuccess) {
        // fallback: 29 separate step launches (CA already holds C0)
        float* cp = CA; float* cn = CB;
        for (int kk = 1; kk < KSEG; ++kk) {
            dp_step_kernel<<<dim3(128, BATCH), 256, 0, stream>>>(Dm, cp, cn, tsum, kk);
            float* tmp = cp; cp = cn; cn = tmp;
        }
    }
    finalize_kernel<<<dim3(NTOK / 256, BATCH), 256, 0, stream>>>(tsum, out);
}

// Round 3
// 1984.232 us; speedup vs baseline: 1.7769x; 1.7769x over previous
//
#include <hip/hip_runtime.h>
#include <hip/hip_bf16.h>
#include <float.h>

// Problem constants (OSG_C_29987461660961)
#define NTOK 2048
#define FDIM 1024
#define HDIM 512
#define EDIM 256
#define BATCH 2
#define KSEG 30
#define NP1 2049
static const size_t ST2 = (size_t)NP1 * NP1;   // Sp per-batch element count

// ---------------------------------------------------------------------------
// Shared NT GEMM: C[i][j] = sum_k A[i*lda+k]*B[j*ldb+k]  (+bias / relu / D-xform)
// ---------------------------------------------------------------------------
template<int MODE>
__global__ __launch_bounds__(256)
void gemm_nt(const float* __restrict__ A, int lda, size_t strideA,
             const float* __restrict__ Bm, int ldb, size_t strideB,
             const float* __restrict__ bias,
             float* __restrict__ C, int ldc, size_t strideC,
             int K, const float* __restrict__ dvec)
{
    __shared__ float As[32][68];
    __shared__ float Bs[32][68];
    const int z = blockIdx.z;
    const float* Ab = A + (size_t)z * strideA;
    const float* Bb = Bm + (size_t)z * strideB;
    float* Cb = C + (size_t)z * strideC;

    const int t = threadIdx.x;
    const int tx = t & 15, ty = t >> 4;
    const int lrow = t >> 3, lkv = t & 7;
    const int by = blockIdx.y, bx = blockIdx.x;

    float acc[4][4] = {};
    const int ktiles = K >> 5;
    for (int kt = 0; kt < ktiles; ++kt) {
#pragma unroll
        for (int h = 0; h < 2; ++h) {
            const int r = lrow + h * 32;
            const float4 av = *(const float4*)(Ab + (size_t)(by * 64 + r) * lda + kt * 32 + lkv * 4);
            As[lkv * 4 + 0][r] = av.x; As[lkv * 4 + 1][r] = av.y;
            As[lkv * 4 + 2][r] = av.z; As[lkv * 4 + 3][r] = av.w;
            const float4 bv = *(const float4*)(Bb + (size_t)(bx * 64 + r) * ldb + kt * 32 + lkv * 4);
            Bs[lkv * 4 + 0][r] = bv.x; Bs[lkv * 4 + 1][r] = bv.y;
            Bs[lkv * 4 + 2][r] = bv.z; Bs[lkv * 4 + 3][r] = bv.w;
        }
        __syncthreads();
#pragma unroll
        for (int kk = 0; kk < 32; ++kk) {
            const float4 a = *(const float4*)&As[kk][ty * 4];
            const float4 b = *(const float4*)&Bs[kk][tx * 4];
            const float ar[4] = {a.x, a.y, a.z, a.w};
            const float br[4] = {b.x, b.y, b.z, b.w};
#pragma unroll
            for (int i = 0; i < 4; ++i)
#pragma unroll
                for (int j = 0; j < 4; ++j)
                    acc[i][j] = fmaf(ar[i], br[j], acc[i][j]);
        }
        __syncthreads();
    }

    const int row0 = by * 64 + ty * 4;
    const int col0 = bx * 64 + tx * 4;
    if (MODE == 2) {
        float di[4], dj[4];
#pragma unroll
        for (int i = 0; i < 4; ++i) di[i] = dvec[z * NTOK + row0 + i];
#pragma unroll
        for (int j = 0; j < 4; ++j) dj[j] = dvec[z * NTOK + col0 + j];
#pragma unroll
        for (int i = 0; i < 4; ++i) {
            float4 v;
            float o[4];
#pragma unroll
            for (int j = 0; j < 4; ++j) {
                const float den = sqrtf(fmaxf(di[i] * dj[j], 1e-8f));
                o[j] = 0.5f * (1.0f - acc[i][j] / den);
            }
            v.x = o[0]; v.y = o[1]; v.z = o[2]; v.w = o[3];
            *(float4*)(Cb + (size_t)(row0 + i) * ldc + col0) = v;
        }
    } else {
#pragma unroll
        for (int i = 0; i < 4; ++i) {
            float o[4];
#pragma unroll
            for (int j = 0; j < 4; ++j) {
                float v = acc[i][j] + bias[col0 + j];
                if (MODE == 0) v = fmaxf(v, 0.0f);
                o[j] = v;
            }
            float4 v4; v4.x = o[0]; v4.y = o[1]; v4.z = o[2]; v4.w = o[3];
            *(float4*)(Cb + (size_t)(row0 + i) * ldc + col0) = v4;
        }
    }
}

__global__ __launch_bounds__(256)
void rownorm_kernel(const float* __restrict__ e, float* __restrict__ dvec)
{
    const int wid = (blockIdx.x * 256 + threadIdx.x) >> 6;
    const int lane = threadIdx.x & 63;
    if (wid >= BATCH * NTOK) return;
    const float4 v = *(const float4*)(e + (size_t)wid * EDIM + lane * 4);
    float s = v.x * v.x + v.y * v.y + v.z * v.z + v.w * v.w;
#pragma unroll
    for (int off = 32; off; off >>= 1) s += __shfl_xor(s, off);
    if (lane == 0) dvec[wid] = s;
}

// Row-wise inclusive scan of D (f32) into Sp rows 1..N (f64). Sp[r][0]=0.
__global__ __launch_bounds__(256)
void sat_row_kernel(const float* __restrict__ D, double* __restrict__ Sp)
{
    const int b = blockIdx.y;
    const int r = blockIdx.x + 1;
    const float* drow = D + (size_t)b * NTOK * NTOK + (size_t)(r - 1) * NTOK;
    double* sprow = Sp + (size_t)b * ST2 + (size_t)r * NP1;
    const int t = threadIdx.x, lane = t & 63, wv = t >> 6;
    __shared__ double wtot[4];
    double carry = 0.0;
    if (t == 0) sprow[0] = 0.0;
    for (int ch = 0; ch < NTOK / 256; ++ch) {
        double v = (double)drow[ch * 256 + t];
#pragma unroll
        for (int d = 1; d < 64; d <<= 1) {
            const double u = __shfl_up(v, (unsigned)d, 64);
            if (lane >= d) v += u;
        }
        if (lane == 63) wtot[wv] = v;
        __syncthreads();
        double pre = carry;
        for (int ww = 0; ww < wv; ++ww) pre += wtot[ww];
        const double tot = carry + wtot[0] + wtot[1] + wtot[2] + wtot[3];
        sprow[ch * 256 + t + 1] = v + pre;
        __syncthreads();
        carry = tot;
    }
}

// Column cumsum of Sp in 3 phases (strips of 256 rows).
__global__ void satc1(const double* __restrict__ Sp, double* __restrict__ aux)
{
    const int b = blockIdx.z, s = blockIdx.y;
    const int c = blockIdx.x * 256 + threadIdx.x;
    if (c > NTOK) return;
    const double* sp = Sp + (size_t)b * ST2;
    double tt = 0.0;
    const int r0 = s * 256 + 1;
    for (int r = r0; r < r0 + 256; ++r) tt += sp[(size_t)r * NP1 + c];
    aux[(size_t)(b * 8 + s) * NP1 + c] = tt;
}
__global__ void satc2(double* __restrict__ aux)
{
    const int b = blockIdx.y;
    const int c = blockIdx.x * 256 + threadIdx.x;
    if (c > NTOK) return;
    double run = 0.0;
    for (int s = 0; s < 8; ++s) {
        const size_t id = (size_t)(b * 8 + s) * NP1 + c;
        const double tt = aux[id]; aux[id] = run; run += tt;
    }
}
__global__ void satc3(double* __restrict__ Sp, const double* __restrict__ aux)
{
    const int b = blockIdx.z, s = blockIdx.y;
    const int c = blockIdx.x * 256 + threadIdx.x;
    if (c > NTOK) return;
    double* sp = Sp + (size_t)b * ST2;
    if (s == 0) sp[c] = 0.0;
    double run = aux[(size_t)(b * 8 + s) * NP1 + c];
    const int r0 = s * 256 + 1;
    for (int r = r0; r < r0 + 256; ++r) {
        const size_t id = (size_t)r * NP1 + c;
        run += sp[id];
        sp[id] = run;
    }
}

__global__ void diag_kernel(const double* __restrict__ Sp, double* __restrict__ dg)
{
    const int b = blockIdx.y;
    const int t = blockIdx.x * 256 + threadIdx.x;
    if (t <= NTOK) dg[b * NP1 + t] = Sp[(size_t)b * ST2 + (size_t)t * NP1 + t];
}

// Bsum[i][j] = diag[j+1] + diag[i] - 2*Sp[i][j+1] (f64 math -> f32), j >= i.
__global__ __launch_bounds__(256)
void bsum_kernel(const double* __restrict__ Sp, const double* __restrict__ dg,
                 float* __restrict__ Bsum, float* __restrict__ C0)
{
    const int b = blockIdx.y, i = blockIdx.x;
    const double* sprow = Sp + (size_t)b * ST2 + (size_t)i * NP1;
    const double* dgb = dg + (size_t)b * NP1;
    const double di = dgb[i];
    float* brow = Bsum + (size_t)b * NTOK * NTOK + (size_t)i * NTOK;
    for (int j = i + threadIdx.x; j < NTOK; j += 256) {
        const double v = dgb[j + 1] + di - 2.0 * sprow[j + 1];
        brow[j] = (float)v;
        if (j == NTOK - 1) C0[b * NTOK + i] = (float)v;
    }
}

// ---------------------------------------------------------------------------
// Hand-rolled two-level grid barrier. bar layout (ints, 128B-spread):
//   bar[s*32], s=0..7   : sub-counters
//   bar[256]            : root counter
//   bar[288]            : release flag (epoch)
// Requires all blocks co-resident (cooperative launch) and bar zeroed.
// ---------------------------------------------------------------------------
__device__ inline void grid_barrier(int* bar, int epoch)
{
    __syncthreads();
    if (threadIdx.x == 0) {
        __threadfence();   // make this block's global stores device-visible
        const int bid = blockIdx.y * gridDim.x + blockIdx.x;
        const int nblk = gridDim.x * gridDim.y;
        int* subc = bar + (bid & 7) * 32;
        int* root = bar + 256;
        int* flag = bar + 288;
        const int subN = nblk >> 3;
        const int prev = __hip_atomic_fetch_add(subc, 1, __ATOMIC_ACQ_REL, __HIP_MEMORY_SCOPE_AGENT);
        if (prev == subN - 1) {
            __hip_atomic_store(subc, 0, __ATOMIC_RELAXED, __HIP_MEMORY_SCOPE_AGENT);
            const int r = __hip_atomic_fetch_add(root, 1, __ATOMIC_ACQ_REL, __HIP_MEMORY_SCOPE_AGENT);
            if (r == 7) {
                __hip_atomic_store(root, 0, __ATOMIC_RELAXED, __HIP_MEMORY_SCOPE_AGENT);
                __hip_atomic_store(flag, epoch, __ATOMIC_RELEASE, __HIP_MEMORY_SCOPE_AGENT);
            }
        }
        while (__hip_atomic_load(flag, __ATOMIC_ACQUIRE, __HIP_MEMORY_SCOPE_AGENT) < epoch)
            __builtin_amdgcn_s_sleep(1);
        __threadfence();   // invalidate stale cached lines before re-reading C
    }
    __syncthreads();
}

// ---------------------------------------------------------------------------
// Fused DP: all 29 steps, Bsum upper-triangle parked in LDS.
// Grid (128, BATCH) x 256 threads. Each block owns 8 row pairs (p, 2047-p);
// each pair is exactly 2049 Bsum elements. 82KB LDS -> 1 block/CU, 256 blocks
// co-resident via cooperative launch. C vector exchanged via global + custom
// barrier. Per-block softmax column accumulator merged to tsum once at end.
// ---------------------------------------------------------------------------
#define DP_BX 128
#define DP_PAIRS 8

__global__ __launch_bounds__(256)
void dp_fused_kernel(const float* __restrict__ Bsum,
                     float* __restrict__ Ca, float* __restrict__ Cb,
                     float* __restrict__ tsum, int* __restrict__ bar)
{
    __shared__ float rowbuf[DP_PAIRS][2052];
    __shared__ float cs[NTOK];
    __shared__ float acc[NTOK];
    const int b = blockIdx.y;
    const int t = threadIdx.x, lane = t & 63, wv = t >> 6;
    const float* Bb = Bsum + (size_t)b * NTOK * NTOK;
    const int pbase = blockIdx.x * DP_PAIRS;

    // coalesced whole-block load of each pair-row (row i0 cols p.., then row i1)
    for (int pr = 0; pr < DP_PAIRS; ++pr) {
        const int p = pbase + pr;
        const int L0 = NTOK - p;
        const float* r0 = Bb + (size_t)p * NTOK + p;
        const float* r1 = Bb + (size_t)(NTOK - 1 - p) * NTOK;
        for (int idx = t; idx <= NTOK; idx += 256)
            rowbuf[pr][idx] = (idx < L0) ? r0[idx] : r1[idx - 1];
    }
    for (int j = t; j < NTOK; j += 256) acc[j] = 0.0f;
    __syncthreads();
    // C0[i] = Bsum[i][N-1]
    for (int pr = t; pr < DP_PAIRS; pr += 256) {
        const int p = pbase + pr;
        Ca[b * NTOK + p] = rowbuf[pr][NTOK - p - 1];
        Ca[b * NTOK + (NTOK - 1 - p)] = rowbuf[pr][NTOK];
    }
    grid_barrier(bar, 1);

    const float* Cr = Ca;
    float* Cn = Cb;
    for (int k = 1; k < KSEG; ++k) {
        const float* Crb = Cr + b * NTOK;
        for (int j = t; j < NTOK; j += 256)
            cs[j] = (j < NTOK - 1) ? Crb[j + 1] : 0.0f;
        __syncthreads();
        const int jmax = NTOK - k;
        float* Cnb = Cn + b * NTOK;
#pragma unroll
        for (int u = 0; u < 2; ++u) {
            const int pr = wv * 2 + u;
            const int p = pbase + pr;
            const float* rb = rowbuf[pr];
            // ---- row i0 = p (always valid: p <= 1023 < jmax >= 2019) ----
            {
                const int V = jmax - p;
                float mv[32];
                float mn = FLT_MAX;
#pragma unroll
                for (int c = 0; c < 32; ++c) {
                    const int idx = lane + c * 64;
                    float v = FLT_MAX;
                    if (idx < V) v = rb[idx] + cs[p + idx];
                    mv[c] = v;
                    mn = fminf(mn, v);
                }
#pragma unroll
                for (int off = 32; off; off >>= 1) mn = fminf(mn, __shfl_xor(mn, off));
                if (lane == 0) Cnb[p] = mn;
                float s = 0.0f;
#pragma unroll
                for (int c = 0; c < 32; ++c) {
                    const int idx = lane + c * 64;
                    float w = 0.0f;
                    if (idx < V) w = __expf(mn - mv[c]);
                    mv[c] = w;
                    s += w;
                }
#pragma unroll
                for (int off = 32; off; off >>= 1) s += __shfl_xor(s, off);
                const float inv = 1.0f / s;
#pragma unroll
                for (int c = 0; c < 32; ++c) {
                    const int idx = lane + c * 64;
                    if (idx < V) atomicAdd(&acc[p + idx], mv[c] * inv);
                }
            }
            // ---- row i1 = 2047-p (valid iff p >= k) ----
            const int i1 = NTOK - 1 - p;
            if (p >= k) {
                const int V = p + 1 - k;
                const int base = NTOK - p;
                float mv[16];
                float mn = FLT_MAX;
#pragma unroll
                for (int c = 0; c < 16; ++c) {
                    const int idx = lane + c * 64;
                    float v = FLT_MAX;
                    if (idx < V) v = rb[base + idx] + cs[i1 + idx];
                    mv[c] = v;
                    mn = fminf(mn, v);
                }
#pragma unroll
                for (int off = 32; off; off >>= 1) mn = fminf(mn, __shfl_xor(mn, off));
                if (lane == 0) Cnb[i1] = mn;
                float s = 0.0f;
#pragma unroll
                for (int c = 0; c < 16; ++c) {
                    const int idx = lane + c * 64;
                    float w = 0.0f;
                    if (idx < V) w = __expf(mn - mv[c]);
                    mv[c] = w;
                    s += w;
                }
#pragma unroll
                for (int off = 32; off; off >>= 1) s += __shfl_xor(s, off);
                const float inv = 1.0f / s;
#pragma unroll
                for (int c = 0; c < 16; ++c) {
                    const int idx = lane + c * 64;
                    if (idx < V) atomicAdd(&acc[i1 + idx], mv[c] * inv);
                }
            } else if (lane == 0) {
                Cnb[i1] = 0.0f;
            }
        }
        grid_barrier(bar, k + 1);
        float* tmp = (float*)Cr; Cr = Cn; Cn = tmp;
    }
    // merge per-block acc into global tsum
    float* ts = tsum + b * NTOK;
    for (int j = t; j < NTOK; j += 256) {
        const float v = acc[j];
        if (v != 0.0f) atomicAdd(&ts[j], v);
    }
}

// ---- fallback path (29 launches), kept in case cooperative launch fails ----
__global__ __launch_bounds__(256)
void dp_step_kernel(const float* __restrict__ Bsum, const float* __restrict__ Cprev,
                    float* __restrict__ Cnext, float* __restrict__ tsum, int kk)
{
    __shared__ float cs[NTOK];
    __shared__ float acc[NTOK];
    const int b = blockIdx.y;
    const int t = threadIdx.x, lane = t & 63, wv = t >> 6;
    const float* Cp = Cprev + b * NTOK;
    for (int j = t; j < NTOK; j += 256) {
        cs[j] = (j < NTOK - 1) ? Cp[j + 1] : 0.0f;
        acc[j] = 0.0f;
    }
    __syncthreads();
    const int jmax = NTOK - kk;
    const int w = blockIdx.x * 4 + wv;
    const float* Bb = Bsum + (size_t)b * NTOK * NTOK;
    float* Cn = Cnext + b * NTOK;
    const int rows[4] = { w, 1023 - w, 1024 + w, 2047 - w };
#pragma unroll
    for (int rr = 0; rr < 4; ++rr) {
        const int i = rows[rr];
        if (i >= jmax) { if (lane == 0) Cn[i] = 0.0f; continue; }
        const float* brow = Bb + (size_t)i * NTOK;
        const int j0 = i + lane;
        float mv[32];
        float mn = FLT_MAX;
#pragma unroll
        for (int c = 0; c < 32; ++c) {
            const int j = j0 + c * 64;
            float v = FLT_MAX;
            if (j < jmax) v = brow[j] + cs[j];
            mv[c] = v;
            mn = fminf(mn, v);
        }
#pragma unroll
        for (int off = 32; off; off >>= 1) mn = fminf(mn, __shfl_xor(mn, off));
        if (lane == 0) Cn[i] = mn;
        float s = 0.0f;
#pragma unroll
        for (int c = 0; c < 32; ++c) {
            const int j = j0 + c * 64;
            float p = 0.0f;
            if (j < jmax) p = __expf(mn - mv[c]);
            mv[c] = p;
            s += p;
        }
#pragma unroll
        for (int off = 32; off; off >>= 1) s += __shfl_xor(s, off);
        const float inv = 1.0f / s;
#pragma unroll
        for (int c = 0; c < 32; ++c) {
            const int j = j0 + c * 64;
            if (j < jmax) atomicAdd(&acc[j], mv[c] * inv);
        }
    }
    __syncthreads();
    float* ts = tsum + b * NTOK;
    for (int j = t; j < NTOK; j += 256) {
        const float v = acc[j];
        if (v != 0.0f) atomicAdd(&ts[j], v);
    }
}

__global__ void finalize_kernel(const float* __restrict__ tsum, float* __restrict__ out)
{
    const int b = blockIdx.y;
    const int j = blockIdx.x * 256 + threadIdx.x;
    if (j >= NTOK) return;
    float ts = tsum[b * NTOK + j];
    int steps = NTOK - 1 - j;
    if (steps > KSEG - 1) steps = KSEG - 1;
    float tc = (float)(j + 1) * (float)steps;
    if (j == NTOK - 1) { ts += (float)NTOK; tc += (float)NTOK; }
    out[b * NTOK + j] = ts / tc;
}

extern "C" void kernel_launch(void* const* d_in, const int* in_sizes, int n_in,
                              void* d_out, int out_size, void* d_ws, size_t ws_size,
                              hipStream_t stream)
{
    const float* x  = (const float*)d_in[0];
    const float* W0 = (const float*)d_in[1];
    const float* b0 = (const float*)d_in[2];
    const float* W1 = (const float*)d_in[3];
    const float* b1 = (const float*)d_in[4];
    float* out = (float*)d_out;

    char* ws = (char*)d_ws;
    size_t off = 0;
    auto alloc = [&](size_t bytes) -> void* {
        void* p = (void*)(ws + off);
        off += (bytes + 255) & ~(size_t)255;
        return p;
    };
    double* Sp   = (double*)alloc((size_t)BATCH * ST2 * sizeof(double));
    float*  Dm   = (float*) alloc((size_t)BATCH * NTOK * NTOK * sizeof(float));
    float*  h    = (float*) alloc((size_t)BATCH * NTOK * HDIM * sizeof(float));
    float*  e    = (float*) alloc((size_t)BATCH * NTOK * EDIM * sizeof(float));
    float*  dvec = (float*) alloc((size_t)BATCH * NTOK * sizeof(float));
    double* dg   = (double*)alloc((size_t)BATCH * NP1 * sizeof(double));
    double* aux  = (double*)alloc((size_t)BATCH * 8 * NP1 * sizeof(double));
    float*  CA   = (float*) alloc((size_t)BATCH * NTOK * sizeof(float));
    float*  CB   = (float*) alloc((size_t)BATCH * NTOK * sizeof(float));
    float*  tsum = (float*) alloc((size_t)BATCH * NTOK * sizeof(float));
    int*    bar  = (int*)   alloc(512 * sizeof(int));
    (void)ws_size; (void)in_sizes; (void)n_in; (void)out_size;

    hipMemsetAsync(tsum, 0, (size_t)BATCH * NTOK * sizeof(float), stream);
    hipMemsetAsync(bar, 0, 512 * sizeof(int), stream);

    gemm_nt<0><<<dim3(HDIM / 64, (BATCH * NTOK) / 64, 1), 256, 0, stream>>>(
        x, FDIM, 0, W0, FDIM, 0, b0, h, HDIM, 0, FDIM, nullptr);
    gemm_nt<1><<<dim3(EDIM / 64, (BATCH * NTOK) / 64, 1), 256, 0, stream>>>(
        h, HDIM, 0, W1, HDIM, 0, b1, e, EDIM, 0, HDIM, nullptr);
    rownorm_kernel<<<dim3((BATCH * NTOK) / 4), 256, 0, stream>>>(e, dvec);
    gemm_nt<2><<<dim3(NTOK / 64, NTOK / 64, BATCH), 256, 0, stream>>>(
        e, EDIM, (size_t)NTOK * EDIM, e, EDIM, (size_t)NTOK * EDIM, nullptr,
        Dm, NTOK, (size_t)NTOK * NTOK, EDIM, dvec);
    sat_row_kernel<<<dim3(NTOK, BATCH), 256, 0, stream>>>(Dm, Sp);
    satc1<<<dim3((NP1 + 255) / 256, 8, BATCH), 256, 0, stream>>>(Sp, aux);
    satc2<<<dim3((NP1 + 255) / 256, BATCH), 256, 0, stream>>>(aux);
    satc3<<<dim3((NP1 + 255) / 256, 8, BATCH), 256, 0, stream>>>(Sp, aux);
    diag_kernel<<<dim3((NP1 + 255) / 256, BATCH), 256, 0, stream>>>(Sp, dg);
    bsum_kernel<<<dim3(NTOK, BATCH), 256, 0, stream>>>(Sp, dg, Dm, CA);

    // Fused DP (cooperative launch for co-residency; custom barrier inside).
    void* args[] = { (void*)&Dm, (void*)&CA, (void*)&CB, (void*)&tsum, (void*)&bar };
    hipError_t err = hipLaunchCooperativeKernel((const void*)dp_fused_kernel,
                                                dim3(DP_BX, BATCH), dim3(256),
                                                args, 0, stream);
    if (err != hipSuccess) {
        // fallback: 29 separate step launches (CA already holds C0 from bsum_kernel)
        float* cp = CA; float* cn = CB;
        for (int kk = 1; kk < KSEG; ++kk) {
            dp_step_kernel<<<dim3(128, BATCH), 256, 0, stream>>>(Dm, cp, cn, tsum, kk);
            float* tmp = cp; cp = cn; cn = tmp;
        }
    }
    finalize_kernel<<<dim3(NTOK / 256, BATCH), 256, 0, stream>>>(tsum, out);
}

// Round 4
// 1444.645 us; speedup vs baseline: 2.4405x; 1.3735x over previous
//
#include <hip/hip_runtime.h>
#include <hip/hip_bf16.h>
#include <float.h>

// Problem constants (OSG_C_29987461660961)
#define NTOK 2048
#define FDIM 1024
#define HDIM 512
#define EDIM 256
#define BATCH 2
#define KSEG 30
#define NP1 2049
static const size_t ST2 = (size_t)NP1 * NP1;   // Sp per-batch element count

// ---------------------------------------------------------------------------
// Shared NT GEMM: C[i][j] = sum_k A[i*lda+k]*B[j*ldb+k]  (+bias / relu / D-xform)
// ---------------------------------------------------------------------------
template<int MODE>
__global__ __launch_bounds__(256)
void gemm_nt(const float* __restrict__ A, int lda, size_t strideA,
             const float* __restrict__ Bm, int ldb, size_t strideB,
             const float* __restrict__ bias,
             float* __restrict__ C, int ldc, size_t strideC,
             int K, const float* __restrict__ dvec)
{
    __shared__ float As[32][68];
    __shared__ float Bs[32][68];
    const int z = blockIdx.z;
    const float* Ab = A + (size_t)z * strideA;
    const float* Bb = Bm + (size_t)z * strideB;
    float* Cb = C + (size_t)z * strideC;

    const int t = threadIdx.x;
    const int tx = t & 15, ty = t >> 4;
    const int lrow = t >> 3, lkv = t & 7;
    const int by = blockIdx.y, bx = blockIdx.x;

    float acc[4][4] = {};
    const int ktiles = K >> 5;
    for (int kt = 0; kt < ktiles; ++kt) {
#pragma unroll
        for (int h = 0; h < 2; ++h) {
            const int r = lrow + h * 32;
            const float4 av = *(const float4*)(Ab + (size_t)(by * 64 + r) * lda + kt * 32 + lkv * 4);
            As[lkv * 4 + 0][r] = av.x; As[lkv * 4 + 1][r] = av.y;
            As[lkv * 4 + 2][r] = av.z; As[lkv * 4 + 3][r] = av.w;
            const float4 bv = *(const float4*)(Bb + (size_t)(bx * 64 + r) * ldb + kt * 32 + lkv * 4);
            Bs[lkv * 4 + 0][r] = bv.x; Bs[lkv * 4 + 1][r] = bv.y;
            Bs[lkv * 4 + 2][r] = bv.z; Bs[lkv * 4 + 3][r] = bv.w;
        }
        __syncthreads();
#pragma unroll
        for (int kk = 0; kk < 32; ++kk) {
            const float4 a = *(const float4*)&As[kk][ty * 4];
            const float4 b = *(const float4*)&Bs[kk][tx * 4];
            const float ar[4] = {a.x, a.y, a.z, a.w};
            const float br[4] = {b.x, b.y, b.z, b.w};
#pragma unroll
            for (int i = 0; i < 4; ++i)
#pragma unroll
                for (int j = 0; j < 4; ++j)
                    acc[i][j] = fmaf(ar[i], br[j], acc[i][j]);
        }
        __syncthreads();
    }

    const int row0 = by * 64 + ty * 4;
    const int col0 = bx * 64 + tx * 4;
    if (MODE == 2) {
        float di[4], dj[4];
#pragma unroll
        for (int i = 0; i < 4; ++i) di[i] = dvec[z * NTOK + row0 + i];
#pragma unroll
        for (int j = 0; j < 4; ++j) dj[j] = dvec[z * NTOK + col0 + j];
#pragma unroll
        for (int i = 0; i < 4; ++i) {
            float4 v;
            float o[4];
#pragma unroll
            for (int j = 0; j < 4; ++j) {
                const float den = sqrtf(fmaxf(di[i] * dj[j], 1e-8f));
                o[j] = 0.5f * (1.0f - acc[i][j] / den);
            }
            v.x = o[0]; v.y = o[1]; v.z = o[2]; v.w = o[3];
            *(float4*)(Cb + (size_t)(row0 + i) * ldc + col0) = v;
        }
    } else {
#pragma unroll
        for (int i = 0; i < 4; ++i) {
            float o[4];
#pragma unroll
            for (int j = 0; j < 4; ++j) {
                float v = acc[i][j] + bias[col0 + j];
                if (MODE == 0) v = fmaxf(v, 0.0f);
                o[j] = v;
            }
            float4 v4; v4.x = o[0]; v4.y = o[1]; v4.z = o[2]; v4.w = o[3];
            *(float4*)(Cb + (size_t)(row0 + i) * ldc + col0) = v4;
        }
    }
}

__global__ __launch_bounds__(256)
void rownorm_kernel(const float* __restrict__ e, float* __restrict__ dvec)
{
    const int wid = (blockIdx.x * 256 + threadIdx.x) >> 6;
    const int lane = threadIdx.x & 63;
    if (wid >= BATCH * NTOK) return;
    const float4 v = *(const float4*)(e + (size_t)wid * EDIM + lane * 4);
    float s = v.x * v.x + v.y * v.y + v.z * v.z + v.w * v.w;
#pragma unroll
    for (int off = 32; off; off >>= 1) s += __shfl_xor(s, off);
    if (lane == 0) dvec[wid] = s;
}

// Row-wise inclusive scan of D (f32) into Sp rows 1..N (f64). Sp[r][0]=0.
__global__ __launch_bounds__(256)
void sat_row_kernel(const float* __restrict__ D, double* __restrict__ Sp)
{
    const int b = blockIdx.y;
    const int r = blockIdx.x + 1;
    const float* drow = D + (size_t)b * NTOK * NTOK + (size_t)(r - 1) * NTOK;
    double* sprow = Sp + (size_t)b * ST2 + (size_t)r * NP1;
    const int t = threadIdx.x, lane = t & 63, wv = t >> 6;
    __shared__ double wtot[4];
    double carry = 0.0;
    if (t == 0) sprow[0] = 0.0;
    for (int ch = 0; ch < NTOK / 256; ++ch) {
        double v = (double)drow[ch * 256 + t];
#pragma unroll
        for (int d = 1; d < 64; d <<= 1) {
            const double u = __shfl_up(v, (unsigned)d, 64);
            if (lane >= d) v += u;
        }
        if (lane == 63) wtot[wv] = v;
        __syncthreads();
        double pre = carry;
        for (int ww = 0; ww < wv; ++ww) pre += wtot[ww];
        const double tot = carry + wtot[0] + wtot[1] + wtot[2] + wtot[3];
        sprow[ch * 256 + t + 1] = v + pre;
        __syncthreads();
        carry = tot;
    }
}

// Column cumsum of Sp in 3 phases (strips of 256 rows).
__global__ void satc1(const double* __restrict__ Sp, double* __restrict__ aux)
{
    const int b = blockIdx.z, s = blockIdx.y;
    const int c = blockIdx.x * 256 + threadIdx.x;
    if (c > NTOK) return;
    const double* sp = Sp + (size_t)b * ST2;
    double tt = 0.0;
    const int r0 = s * 256 + 1;
    for (int r = r0; r < r0 + 256; ++r) tt += sp[(size_t)r * NP1 + c];
    aux[(size_t)(b * 8 + s) * NP1 + c] = tt;
}
__global__ void satc2(double* __restrict__ aux)
{
    const int b = blockIdx.y;
    const int c = blockIdx.x * 256 + threadIdx.x;
    if (c > NTOK) return;
    double run = 0.0;
    for (int s = 0; s < 8; ++s) {
        const size_t id = (size_t)(b * 8 + s) * NP1 + c;
        const double tt = aux[id]; aux[id] = run; run += tt;
    }
}
__global__ void satc3(double* __restrict__ Sp, const double* __restrict__ aux)
{
    const int b = blockIdx.z, s = blockIdx.y;
    const int c = blockIdx.x * 256 + threadIdx.x;
    if (c > NTOK) return;
    double* sp = Sp + (size_t)b * ST2;
    if (s == 0) sp[c] = 0.0;
    double run = aux[(size_t)(b * 8 + s) * NP1 + c];
    const int r0 = s * 256 + 1;
    for (int r = r0; r < r0 + 256; ++r) {
        const size_t id = (size_t)r * NP1 + c;
        run += sp[id];
        sp[id] = run;
    }
}

__global__ void diag_kernel(const double* __restrict__ Sp, double* __restrict__ dg)
{
    const int b = blockIdx.y;
    const int t = blockIdx.x * 256 + threadIdx.x;
    if (t <= NTOK) dg[b * NP1 + t] = Sp[(size_t)b * ST2 + (size_t)t * NP1 + t];
}

// Bsum[i][j] = diag[j+1] + diag[i] - 2*Sp[i][j+1] (f64 math -> f32), j >= i.
__global__ __launch_bounds__(256)
void bsum_kernel(const double* __restrict__ Sp, const double* __restrict__ dg,
                 float* __restrict__ Bsum, float* __restrict__ C0)
{
    const int b = blockIdx.y, i = blockIdx.x;
    const double* sprow = Sp + (size_t)b * ST2 + (size_t)i * NP1;
    const double* dgb = dg + (size_t)b * NP1;
    const double di = dgb[i];
    float* brow = Bsum + (size_t)b * NTOK * NTOK + (size_t)i * NTOK;
    for (int j = i + threadIdx.x; j < NTOK; j += 256) {
        const double v = dgb[j + 1] + di - 2.0 * sprow[j + 1];
        brow[j] = (float)v;
        if (j == NTOK - 1) C0[b * NTOK + i] = (float)v;
    }
}

// ---------------------------------------------------------------------------
// Grid barrier v2. All cache maintenance hoisted out of spin/arrive paths:
//  - data exchanged around the barrier uses RELAXED AGENT atomics (coherence
//    point directly, no L2 dirty/stale lines)
//  - poll is RELAXED + s_sleep; ONE acquire fence after detection
//  - arrive RMW is ACQ_REL (its wbl2 has nothing to flush)
// bar layout: bar[s*64] s=0..15 sub-counters (256B apart), bar[1024] root,
// bar[1088] flag. Requires all blocks co-resident + bar zeroed.
// ---------------------------------------------------------------------------
__device__ inline void grid_barrier(int* bar, int epoch)
{
    __syncthreads();   // compiler drains vmcnt/lgkmcnt before s_barrier
    if (threadIdx.x == 0) {
        const int bid = blockIdx.y * gridDim.x + blockIdx.x;
        const int nblk = gridDim.x * gridDim.y;
        int* subc = bar + (bid & 15) * 64;
        int* root = bar + 1024;
        int* flag = bar + 1088;
        const int subN = nblk >> 4;
        const int prev = __hip_atomic_fetch_add(subc, 1, __ATOMIC_ACQ_REL, __HIP_MEMORY_SCOPE_AGENT);
        if (prev == subN - 1) {
            __hip_atomic_store(subc, 0, __ATOMIC_RELAXED, __HIP_MEMORY_SCOPE_AGENT);
            const int r = __hip_atomic_fetch_add(root, 1, __ATOMIC_ACQ_REL, __HIP_MEMORY_SCOPE_AGENT);
            if (r == 15) {
                __hip_atomic_store(root, 0, __ATOMIC_RELAXED, __HIP_MEMORY_SCOPE_AGENT);
                __hip_atomic_store(flag, epoch, __ATOMIC_RELEASE, __HIP_MEMORY_SCOPE_AGENT);
            }
        }
        while (__hip_atomic_load(flag, __ATOMIC_RELAXED, __HIP_MEMORY_SCOPE_AGENT) < epoch)
            __builtin_amdgcn_s_sleep(2);
        __builtin_amdgcn_fence(__ATOMIC_ACQUIRE, "agent");  // one inv, not per-poll
    }
    __syncthreads();
}

__device__ inline void cstore(float* p, float v)
{
    __hip_atomic_store(p, v, __ATOMIC_RELAXED, __HIP_MEMORY_SCOPE_AGENT);
}
__device__ inline float cload(const float* p)
{
    return __hip_atomic_load(p, __ATOMIC_RELAXED, __HIP_MEMORY_SCOPE_AGENT);
}

// ---------------------------------------------------------------------------
// Fused DP: all 29 steps, Bsum upper-triangle parked in LDS.
// Grid (128, BATCH) x 256 threads, 8 row pairs (p, 2047-p) per block,
// 82KB LDS -> 1 block/CU, 256 blocks co-resident (cooperative launch).
// ---------------------------------------------------------------------------
#define DP_BX 128
#define DP_PAIRS 8

__global__ __launch_bounds__(256)
void dp_fused_kernel(const float* __restrict__ Bsum,
                     float* __restrict__ Ca, float* __restrict__ Cb,
                     float* __restrict__ tsum, int* __restrict__ bar)
{
    __shared__ float rowbuf[DP_PAIRS][2052];
    __shared__ float cs[NTOK];
    __shared__ float acc[NTOK];
    const int b = blockIdx.y;
    const int t = threadIdx.x, lane = t & 63, wv = t >> 6;
    const float* Bb = Bsum + (size_t)b * NTOK * NTOK;
    const int pbase = blockIdx.x * DP_PAIRS;

    // coalesced whole-block load of each pair-row (row i0 cols p.., then row i1)
    for (int pr = 0; pr < DP_PAIRS; ++pr) {
        const int p = pbase + pr;
        const int L0 = NTOK - p;
        const float* r0 = Bb + (size_t)p * NTOK + p;
        const float* r1 = Bb + (size_t)(NTOK - 1 - p) * NTOK;
        for (int idx = t; idx <= NTOK; idx += 256)
            rowbuf[pr][idx] = (idx < L0) ? r0[idx] : r1[idx - 1];
    }
    for (int j = t; j < NTOK; j += 256) acc[j] = 0.0f;
    __syncthreads();
    // C0[i] = Bsum[i][N-1]
    for (int pr = t; pr < DP_PAIRS; pr += 256) {
        const int p = pbase + pr;
        cstore(&Ca[b * NTOK + p], rowbuf[pr][NTOK - p - 1]);
        cstore(&Ca[b * NTOK + (NTOK - 1 - p)], rowbuf[pr][NTOK]);
    }
    grid_barrier(bar, 1);

    const float* Cr = Ca;
    float* Cn = Cb;
    for (int k = 1; k < KSEG; ++k) {
        const float* Crb = Cr + b * NTOK;
        for (int j = t; j < NTOK; j += 256)
            cs[j] = (j < NTOK - 1) ? cload(&Crb[j + 1]) : 0.0f;
        __syncthreads();
        const int jmax = NTOK - k;
        float* Cnb = Cn + b * NTOK;
#pragma unroll
        for (int u = 0; u < 2; ++u) {
            const int pr = wv * 2 + u;
            const int p = pbase + pr;
            const float* rb = rowbuf[pr];
            // ---- row i0 = p (always valid) ----
            {
                const int V = jmax - p;
                float mv[32];
                float mn = FLT_MAX;
#pragma unroll
                for (int c = 0; c < 32; ++c) {
                    const int idx = lane + c * 64;
                    float v = FLT_MAX;
                    if (idx < V) v = rb[idx] + cs[p + idx];
                    mv[c] = v;
                    mn = fminf(mn, v);
                }
#pragma unroll
                for (int off = 32; off; off >>= 1) mn = fminf(mn, __shfl_xor(mn, off));
                if (lane == 0) cstore(&Cnb[p], mn);
                float s = 0.0f;
#pragma unroll
                for (int c = 0; c < 32; ++c) {
                    const int idx = lane + c * 64;
                    float w = 0.0f;
                    if (idx < V) w = __expf(mn - mv[c]);
                    mv[c] = w;
                    s += w;
                }
#pragma unroll
                for (int off = 32; off; off >>= 1) s += __shfl_xor(s, off);
                const float inv = 1.0f / s;
#pragma unroll
                for (int c = 0; c < 32; ++c) {
                    const int idx = lane + c * 64;
                    if (idx < V) atomicAdd(&acc[p + idx], mv[c] * inv);
                }
            }
            // ---- row i1 = 2047-p (valid iff p >= k) ----
            const int i1 = NTOK - 1 - p;
            if (p >= k) {
                const int V = p + 1 - k;
                const int base = NTOK - p;
                float mv[16];
                float mn = FLT_MAX;
#pragma unroll
                for (int c = 0; c < 16; ++c) {
                    const int idx = lane + c * 64;
                    float v = FLT_MAX;
                    if (idx < V) v = rb[base + idx] + cs[i1 + idx];
                    mv[c] = v;
                    mn = fminf(mn, v);
                }
#pragma unroll
                for (int off = 32; off; off >>= 1) mn = fminf(mn, __shfl_xor(mn, off));
                if (lane == 0) cstore(&Cnb[i1], mn);
                float s = 0.0f;
#pragma unroll
                for (int c = 0; c < 16; ++c) {
                    const int idx = lane + c * 64;
                    float w = 0.0f;
                    if (idx < V) w = __expf(mn - mv[c]);
                    mv[c] = w;
                    s += w;
                }
#pragma unroll
                for (int off = 32; off; off >>= 1) s += __shfl_xor(s, off);
                const float inv = 1.0f / s;
#pragma unroll
                for (int c = 0; c < 16; ++c) {
                    const int idx = lane + c * 64;
                    if (idx < V) atomicAdd(&acc[i1 + idx], mv[c] * inv);
                }
            } else if (lane == 0) {
                cstore(&Cnb[i1], 0.0f);
            }
        }
        grid_barrier(bar, k + 1);
        float* tmp = (float*)Cr; Cr = Cn; Cn = tmp;
    }
    // merge per-block acc into global tsum
    float* ts = tsum + b * NTOK;
    for (int j = t; j < NTOK; j += 256) {
        const float v = acc[j];
        if (v != 0.0f) atomicAdd(&ts[j], v);
    }
}

// ---- fallback path (29 launches), kept in case cooperative launch fails ----
__global__ __launch_bounds__(256)
void dp_step_kernel(const float* __restrict__ Bsum, const float* __restrict__ Cprev,
                    float* __restrict__ Cnext, float* __restrict__ tsum, int kk)
{
    __shared__ float cs[NTOK];
    __shared__ float acc[NTOK];
    const int b = blockIdx.y;
    const int t = threadIdx.x, lane = t & 63, wv = t >> 6;
    const float* Cp = Cprev + b * NTOK;
    for (int j = t; j < NTOK; j += 256) {
        cs[j] = (j < NTOK - 1) ? Cp[j + 1] : 0.0f;
        acc[j] = 0.0f;
    }
    __syncthreads();
    const int jmax = NTOK - kk;
    const int w = blockIdx.x * 4 + wv;
    const float* Bb = Bsum + (size_t)b * NTOK * NTOK;
    float* Cn = Cnext + b * NTOK;
    const int rows[4] = { w, 1023 - w, 1024 + w, 2047 - w };
#pragma unroll
    for (int rr = 0; rr < 4; ++rr) {
        const int i = rows[rr];
        if (i >= jmax) { if (lane == 0) Cn[i] = 0.0f; continue; }
        const float* brow = Bb + (size_t)i * NTOK;
        const int j0 = i + lane;
        float mv[32];
        float mn = FLT_MAX;
#pragma unroll
        for (int c = 0; c < 32; ++c) {
            const int j = j0 + c * 64;
            float v = FLT_MAX;
            if (j < jmax) v = brow[j] + cs[j];
            mv[c] = v;
            mn = fminf(mn, v);
        }
#pragma unroll
        for (int off = 32; off; off >>= 1) mn = fminf(mn, __shfl_xor(mn, off));
        if (lane == 0) Cn[i] = mn;
        float s = 0.0f;
#pragma unroll
        for (int c = 0; c < 32; ++c) {
            const int j = j0 + c * 64;
            float p = 0.0f;
            if (j < jmax) p = __expf(mn - mv[c]);
            mv[c] = p;
            s += p;
        }
#pragma unroll
        for (int off = 32; off; off >>= 1) s += __shfl_xor(s, off);
        const float inv = 1.0f / s;
#pragma unroll
        for (int c = 0; c < 32; ++c) {
            const int j = j0 + c * 64;
            if (j < jmax) atomicAdd(&acc[j], mv[c] * inv);
        }
    }
    __syncthreads();
    float* ts = tsum + b * NTOK;
    for (int j = t; j < NTOK; j += 256) {
        const float v = acc[j];
        if (v != 0.0f) atomicAdd(&ts[j], v);
    }
}

__global__ void finalize_kernel(const float* __restrict__ tsum, float* __restrict__ out)
{
    const int b = blockIdx.y;
    const int j = blockIdx.x * 256 + threadIdx.x;
    if (j >= NTOK) return;
    float ts = tsum[b * NTOK + j];
    int steps = NTOK - 1 - j;
    if (steps > KSEG - 1) steps = KSEG - 1;
    float tc = (float)(j + 1) * (float)steps;
    if (j == NTOK - 1) { ts += (float)NTOK; tc += (float)NTOK; }
    out[b * NTOK + j] = ts / tc;
}

extern "C" void kernel_launch(void* const* d_in, const int* in_sizes, int n_in,
                              void* d_out, int out_size, void* d_ws, size_t ws_size,
                              hipStream_t stream)
{
    const float* x  = (const float*)d_in[0];
    const float* W0 = (const float*)d_in[1];
    const float* b0 = (const float*)d_in[2];
    const float* W1 = (const float*)d_in[3];
    const float* b1 = (const float*)d_in[4];
    float* out = (float*)d_out;

    char* ws = (char*)d_ws;
    size_t off = 0;
    auto alloc = [&](size_t bytes) -> void* {
        void* p = (void*)(ws + off);
        off += (bytes + 255) & ~(size_t)255;
        return p;
    };
    double* Sp   = (double*)alloc((size_t)BATCH * ST2 * sizeof(double));
    float*  Dm   = (float*) alloc((size_t)BATCH * NTOK * NTOK * sizeof(float));
    float*  h    = (float*) alloc((size_t)BATCH * NTOK * HDIM * sizeof(float));
    float*  e    = (float*) alloc((size_t)BATCH * NTOK * EDIM * sizeof(float));
    float*  dvec = (float*) alloc((size_t)BATCH * NTOK * sizeof(float));
    double* dg   = (double*)alloc((size_t)BATCH * NP1 * sizeof(double));
    double* aux  = (double*)alloc((size_t)BATCH * 8 * NP1 * sizeof(double));
    float*  CA   = (float*) alloc((size_t)BATCH * NTOK * sizeof(float));
    float*  CB   = (float*) alloc((size_t)BATCH * NTOK * sizeof(float));
    float*  tsum = (float*) alloc((size_t)BATCH * NTOK * sizeof(float));
    int*    bar  = (int*)   alloc(2048 * sizeof(int));
    (void)ws_size; (void)in_sizes; (void)n_in; (void)out_size;

    hipMemsetAsync(tsum, 0, (size_t)BATCH * NTOK * sizeof(float), stream);
    hipMemsetAsync(bar, 0, 2048 * sizeof(int), stream);

    gemm_nt<0><<<dim3(HDIM / 64, (BATCH * NTOK) / 64, 1), 256, 0, stream>>>(
        x, FDIM, 0, W0, FDIM, 0, b0, h, HDIM, 0, FDIM, nullptr);
    gemm_nt<1><<<dim3(EDIM / 64, (BATCH * NTOK) / 64, 1), 256, 0, stream>>>(
        h, HDIM, 0, W1, HDIM, 0, b1, e, EDIM, 0, HDIM, nullptr);
    rownorm_kernel<<<dim3((BATCH * NTOK) / 4), 256, 0, stream>>>(e, dvec);
    gemm_nt<2><<<dim3(NTOK / 64, NTOK / 64, BATCH), 256, 0, stream>>>(
        e, EDIM, (size_t)NTOK * EDIM, e, EDIM, (size_t)NTOK * EDIM, nullptr,
        Dm, NTOK, (size_t)NTOK * NTOK, EDIM, dvec);
    sat_row_kernel<<<dim3(NTOK, BATCH), 256, 0, stream>>>(Dm, Sp);
    satc1<<<dim3((NP1 + 255) / 256, 8, BATCH), 256, 0, stream>>>(Sp, aux);
    satc2<<<dim3((NP1 + 255) / 256, BATCH), 256, 0, stream>>>(aux);
    satc3<<<dim3((NP1 + 255) / 256, 8, BATCH), 256, 0, stream>>>(Sp, aux);
    diag_kernel<<<dim3((NP1 + 255) / 256, BATCH), 256, 0, stream>>>(Sp, dg);
    bsum_kernel<<<dim3(NTOK, BATCH), 256, 0, stream>>>(Sp, dg, Dm, CA);

    // Fused DP (cooperative launch for co-residency; custom barrier inside).
    void* args[] = { (void*)&Dm, (void*)&CA, (void*)&CB, (void*)&tsum, (void*)&bar };
    hipError_t err = hipLaunchCooperativeKernel((const void*)dp_fused_kernel,
                                                dim3(DP_BX, BATCH), dim3(256),
                                                args, 0, stream);
    if (err != hipSuccess) {
        // fallback: 29 separate step launches (CA already holds C0 from bsum_kernel)
        float* cp = CA; float* cn = CB;
        for (int kk = 1; kk < KSEG; ++kk) {
            dp_step_kernel<<<dim3(128, BATCH), 256, 0, stream>>>(Dm, cp, cn, tsum, kk);
            float* tmp = cp; cp = cn; cn = tmp;
        }
    }
    finalize_kernel<<<dim3(NTOK / 256, BATCH), 256, 0, stream>>>(tsum, out);
}